// Round 13
// baseline (75.849 us; speedup 1.0000x reference)
//
#include <hip/hip_runtime.h>

#define DIN 48
#define DOUT 16
#define DC 32      // combined output dims: [mu(16) | logstd(16)]
#define BSH 7      // bucket shift: 128 nodes per bucket
#define BNODES 128
#define NBP 1024   // padded bucket count (power of 2, >= nb)
#define EPB 8192   // edges per binning block
#define TPB_BIN 1024
#define CAPB 4096  // fixed per-bucket region capacity (mean 2046, +45 sigma)
#define XS 49      // padded LDS stride for x tile (conflict-free)

typedef unsigned int uint;
typedef unsigned short ushort;
typedef float f32x4 __attribute__((ext_vector_type(4)));

__device__ __forceinline__ float b2f(ushort u) {
    union { uint i; float f; } v; v.i = ((uint)u) << 16; return v.f;
}
__device__ __forceinline__ ushort f2b(float f) {
    union { float f; uint i; } v; v.f = f;
    uint b = v.i;
    return (ushort)((b + 0x7FFFu + ((b >> 16) & 1u)) >> 16);  // round-to-nearest-even
}

// ---------- binning with atomic region reservation; edges cached in registers ----------

__global__ __launch_bounds__(TPB_BIN) void k_bin2(
        const int* __restrict__ src, const int* __restrict__ dst,
        int* __restrict__ bfill, uint* __restrict__ ebuf, int e_cnt, int nb) {
    __shared__ uint stageV[EPB];              // 32KB
    __shared__ ushort stageB[EPB];            // 16KB
    __shared__ int hist[NBP];                 // 4KB (reused as local fill)
    __shared__ int lofs[NBP];                 // 4KB
    __shared__ int gbase[NBP];                // 4KB
    __shared__ int wtot[16], woff[16];

    int t = threadIdx.x;
    int e0 = blockIdx.x * EPB;
    int ec = min(EPB, e_cnt - e0);

    hist[t] = 0;
    __syncthreads();

    // pass A: load edges ONCE into registers + local bucket histogram
    uint pv[8]; ushort pb[8];
#pragma unroll
    for (int it = 0; it < 8; ++it) {
        int k = t + TPB_BIN * it;
        if (k < ec) {
            int d = dst[e0 + k], s = src[e0 + k];
            int b = d >> BSH;
            pv[it] = ((uint)(d & (BNODES - 1)) << 17) | (uint)s;
            pb[it] = (ushort)b;
            atomicAdd(&hist[b], 1);
        }
    }
    __syncthreads();

    // wave-shuffle exclusive scan over 1024 bins (1 bin per thread, 16 waves)
    {
        int v = hist[t];
        int lane = t & 63, wid = t >> 6;
        int s_ = v;
#pragma unroll
        for (int off = 1; off < 64; off <<= 1) {
            int xv = __shfl_up(s_, off);
            if (lane >= off) s_ += xv;
        }
        if (lane == 63) wtot[wid] = s_;
        __syncthreads();
        if (t < 16) {
            int v2 = wtot[t];
            int w2 = v2;
#pragma unroll
            for (int off = 1; off < 16; off <<= 1) {
                int xv = __shfl_up(w2, off);
                if (t >= off) w2 += xv;
            }
            woff[t] = w2 - v2;
        }
        __syncthreads();
        lofs[t] = s_ - v + woff[wid];   // exclusive prefix for own bin
    }

    // reserve per-bucket region space: one atomic per nonempty bucket
    if (t < nb) {
        int h = hist[t];
        if (h > 0) gbase[t] = atomicAdd(&bfill[t], h);
    }
    __syncthreads();
    hist[t] = 0;  // becomes local fill counter
    __syncthreads();
    // pass B: stage packed edges (from registers) in bucket order
#pragma unroll
    for (int it = 0; it < 8; ++it) {
        int k = t + TPB_BIN * it;
        if (k < ec) {
            int b = pb[it];
            int p = atomicAdd(&hist[b], 1);
            int idx = lofs[b] + p;
            stageV[idx] = pv[it];
            stageB[idx] = pb[it];
        }
    }
    __syncthreads();
    // pass C: contiguous-run copy into the bucket's fixed region
    for (int i = t; i < ec; i += TPB_BIN) {
        int b = stageB[i];
        int off = gbase[b] + (i - lofs[b]);
        if (off < CAPB) ebuf[(size_t)b * CAPB + off] = stageV[i];
    }
}

// ---------- fused: per-bucket node sort -> CSR + dinv, then projection ----------

struct SortStage { uint in[CAPB]; int out[CAPB]; };   // 32KB
union SmemU { SortStage s; float xl[BNODES * XS]; };  // xl = 25088B, fits

__global__ __launch_bounds__(256) void k_sortproj(
        const uint* __restrict__ ebuf, const int* __restrict__ bfill,
        const float* __restrict__ x,
        const float* __restrict__ Wmu, const float* __restrict__ Wls,
        uint* __restrict__ nodeinfo, int* __restrict__ esrc,
        float* __restrict__ dinv, ushort* __restrict__ projh, int n, int nb) {
    __shared__ SmemU u;
    __shared__ float Wl[DIN * DC];            // 6144B
    __shared__ int cntl[BNODES], lofs[BNODES], fill[BNODES], sc[BNODES];
    __shared__ float dvl[BNODES];

    int b = blockIdx.x, t = threadIdx.x;
    int base = b << BSH;

    // ---- issue x-tile loads EARLY (async split: consume after sort) ----
    float4 xr[6];
#pragma unroll
    for (int it = 0; it < 6; ++it) {
        int f4 = t + 256 * it;
        int fb = f4 * 4;
        int node = fb / DIN, k2 = fb % DIN;
        int g = base + node;
        if (g < n) xr[it] = *reinterpret_cast<const float4*>(x + (size_t)g * DIN + k2);
    }

    // stage W (independent of sort phase)
    for (int idx = t; idx < DIN * DC; idx += 256) {
        int k = idx >> 5, j = idx & 31;
        Wl[idx] = (j < DOUT) ? Wmu[k * DOUT + j] : Wls[k * DOUT + (j - DOUT)];
    }

    int m = min(bfill[b], CAPB);

    if (t < BNODES) { cntl[t] = 0; fill[t] = 0; }
    __syncthreads();

    // load bucket segment + per-node histogram
    for (int i = t; i < m; i += 256) {
        uint pk = ebuf[(size_t)b * CAPB + i];
        u.s.in[i] = pk;
        atomicAdd(&cntl[pk >> 17], 1);
    }
    __syncthreads();

    // exclusive scan of 128 local counts
    if (t < BNODES) sc[t] = cntl[t];
    __syncthreads();
#pragma unroll
    for (int off = 1; off < BNODES; off <<= 1) {
        int v = (t < BNODES && t >= off) ? sc[t - off] : 0;
        __syncthreads();
        if (t < BNODES) sc[t] += v;
        __syncthreads();
    }
    if (t < BNODES) {
        int lo = sc[t] - cntl[t];
        lofs[t] = lo;
        int d = base + t;
        if (d < n) {
            nodeinfo[d] = (uint)lo | ((uint)cntl[t] << 13);
            float dv = rsqrtf(1.0f + (float)cntl[t]);
            dinv[d] = dv;
            dvl[t] = dv;
        }
    }
    __syncthreads();

    // placement: sorted by local node into stage_out
    for (int i = t; i < m; i += 256) {
        uint pk = u.s.in[i];
        int ln = (int)(pk >> 17);
        int s = (int)(pk & 0x1FFFFu);
        int r = atomicAdd(&fill[ln], 1);
        u.s.out[lofs[ln] + r] = s;
    }
    __syncthreads();

    // coalesced writeback into the bucket's esrc region
    for (int i = t; i < m; i += 256) esrc[(size_t)b * CAPB + i] = u.s.out[i];
    __syncthreads();

    // ---- projection phase: write prefetched x regs into (reused) LDS ----
#pragma unroll
    for (int it = 0; it < 6; ++it) {
        int f4 = t + 256 * it;
        int fb = f4 * 4;
        int node = fb / DIN, k2 = fb % DIN;
        int g = base + node;
        if (g < n) {
            float* p = &u.xl[node * XS + k2];
            p[0] = xr[it].x; p[1] = xr[it].y; p[2] = xr[it].z; p[3] = xr[it].w;
        }
    }
    __syncthreads();

    int nc = t & 7;        // col group: cols nc*4 .. nc*4+3
    int nr = t >> 3;       // node group: nodes nr*4 .. nr*4+3
    int c0 = nc * 4;

    float4 acc[4];
#pragma unroll
    for (int q = 0; q < 4; ++q) acc[q] = make_float4(0.f, 0.f, 0.f, 0.f);

#pragma unroll 4
    for (int k = 0; k < DIN; ++k) {
        float4 w = *reinterpret_cast<const float4*>(&Wl[k * DC + c0]);
#pragma unroll
        for (int q = 0; q < 4; ++q) {
            float xv = u.xl[(nr * 4 + q) * XS + k];
            acc[q].x += xv * w.x;
            acc[q].y += xv * w.y;
            acc[q].z += xv * w.z;
            acc[q].w += xv * w.w;
        }
    }

#pragma unroll
    for (int q = 0; q < 4; ++q) {
        int ln = nr * 4 + q;
        int d = base + ln;
        if (d >= n) continue;
        float dv = dvl[ln];
        ushort4 ph;
        ph.x = f2b(dv * acc[q].x); ph.y = f2b(dv * acc[q].y);
        ph.z = f2b(dv * acc[q].z); ph.w = f2b(dv * acc[q].w);
        *reinterpret_cast<ushort4*>(projh + ((size_t)d << 5) + c0) = ph;
    }
}

// ---------- gather aggregation: nontemporal streaming (esrc, out) to keep projh in L2 ----------
// out[d][j] = bias[j] + dinv[d] * (projh[d][j] + sum_s projh[s][j])

__global__ __launch_bounds__(256) void k_agg5(
        const int* __restrict__ esrc, const uint* __restrict__ nodeinfo,
        const float* __restrict__ dinv, const ushort* __restrict__ projh,
        const float* __restrict__ bmu, const float* __restrict__ bls,
        float* __restrict__ out, int n) {
    int t = threadIdx.x;
    int l = t & 7;             // dim-quad lane: dims l*4 .. l*4+3
    int g = t >> 3;            // node slot within block (0..31)
    int d = blockIdx.x * 32 + g;
    if (d >= n) return;
    uint info = nodeinfo[d];
    int start = (d >> BSH) * CAPB + (int)(info & 0x1FFFu);
    int end = start + (int)(info >> 13);
    int c0 = l * 4;

    // self-loop term (pre-scaled by dinv[d])
    float4 acc;
    {
        ushort4 s4 = *reinterpret_cast<const ushort4*>(projh + ((size_t)d << 5) + c0);
        acc.x = b2f(s4.x); acc.y = b2f(s4.y); acc.z = b2f(s4.z); acc.w = b2f(s4.w);
    }

    int k = start;
    int nxt[8];
    if (k + 8 <= end) {
#pragma unroll
        for (int u2 = 0; u2 < 8; ++u2) nxt[u2] = __builtin_nontemporal_load(&esrc[k + u2]);
    }
    while (k + 8 <= end) {
        int cur[8];
#pragma unroll
        for (int u2 = 0; u2 < 8; ++u2) cur[u2] = nxt[u2];
        int k2 = k + 8;
        if (k2 + 8 <= end) {
#pragma unroll
            for (int u2 = 0; u2 < 8; ++u2) nxt[u2] = __builtin_nontemporal_load(&esrc[k2 + u2]);
        }
        ushort4 p[8];
#pragma unroll
        for (int u2 = 0; u2 < 8; ++u2)
            p[u2] = *reinterpret_cast<const ushort4*>(projh + ((size_t)cur[u2] << 5) + c0);
#pragma unroll
        for (int u2 = 0; u2 < 8; ++u2) {
            acc.x += b2f(p[u2].x); acc.y += b2f(p[u2].y);
            acc.z += b2f(p[u2].z); acc.w += b2f(p[u2].w);
        }
        k = k2;
    }
    for (; k < end; ++k) {
        int s = __builtin_nontemporal_load(&esrc[k]);
        ushort4 pv = *reinterpret_cast<const ushort4*>(projh + ((size_t)s << 5) + c0);
        acc.x += b2f(pv.x); acc.y += b2f(pv.y); acc.z += b2f(pv.z); acc.w += b2f(pv.w);
    }

    float dv = dinv[d];
    float4 bias = (l < 4) ? *reinterpret_cast<const float4*>(bmu + c0)
                          : *reinterpret_cast<const float4*>(bls + (c0 - DOUT));
    f32x4 ov;
    ov.x = bias.x + dv * acc.x; ov.y = bias.y + dv * acc.y;
    ov.z = bias.z + dv * acc.z; ov.w = bias.w + dv * acc.w;
    float* o = (l < 4) ? (out + (size_t)d * DOUT + c0)
                       : (out + (size_t)n * DOUT + (size_t)d * DOUT + (c0 - DOUT));
    __builtin_nontemporal_store(ov, reinterpret_cast<f32x4*>(o));
}

// ---------- fallback (round-1 atomic) path ----------

__global__ void k_init_deg(float* __restrict__ deg, int n) {
    int i = blockIdx.x * blockDim.x + threadIdx.x;
    if (i < n) deg[i] = 1.0f;
}

__global__ void k_count(const int* __restrict__ dst, float* __restrict__ deg, int e_cnt) {
    int e = blockIdx.x * blockDim.x + threadIdx.x;
    if (e < e_cnt) unsafeAtomicAdd(&deg[dst[e]], 1.0f);
}

__global__ void k_projF(const float* __restrict__ x,
                        const float* __restrict__ Wmu, const float* __restrict__ bmu,
                        const float* __restrict__ Wls, const float* __restrict__ bls,
                        float* __restrict__ deg_dinv, float* __restrict__ proj,
                        float* __restrict__ out, int n) {
    __shared__ float Ws[DIN * DC];
    __shared__ float bs[DC];
    int t = threadIdx.x;
    for (int idx = t; idx < DIN * DC; idx += blockDim.x) {
        int k = idx >> 5, j = idx & 31;
        Ws[idx] = (j < DOUT) ? Wmu[k * DOUT + j] : Wls[k * DOUT + (j - DOUT)];
    }
    if (t < DC) bs[t] = (t < DOUT) ? bmu[t] : bls[t - DOUT];
    __syncthreads();
    int i = blockIdx.x * blockDim.x + t;
    if (i >= n) return;
    float xr[DIN];
    const float4* xp = reinterpret_cast<const float4*>(x + (size_t)i * DIN);
#pragma unroll
    for (int q = 0; q < DIN / 4; ++q) {
        float4 v = xp[q];
        xr[4 * q + 0] = v.x; xr[4 * q + 1] = v.y;
        xr[4 * q + 2] = v.z; xr[4 * q + 3] = v.w;
    }
    float acc[DC];
#pragma unroll
    for (int j = 0; j < DC; ++j) acc[j] = 0.0f;
#pragma unroll 4
    for (int k = 0; k < DIN; ++k) {
        float xv = xr[k];
#pragma unroll
        for (int j = 0; j < DC; ++j) acc[j] += xv * Ws[k * DC + j];
    }
    float dv = rsqrtf(deg_dinv[i]);
    deg_dinv[i] = dv;
    float d2 = dv * dv;
    float4* pp = reinterpret_cast<float4*>(proj + (size_t)i * DC);
#pragma unroll
    for (int q = 0; q < DC / 4; ++q) {
        float4 v;
        v.x = acc[4 * q + 0]; v.y = acc[4 * q + 1];
        v.z = acc[4 * q + 2]; v.w = acc[4 * q + 3];
        pp[q] = v;
    }
    float* omu = out + (size_t)i * DOUT;
    float* ols = out + (size_t)n * DOUT + (size_t)i * DOUT;
#pragma unroll
    for (int j = 0; j < DOUT; ++j) omu[j] = bs[j] + d2 * acc[j];
#pragma unroll
    for (int j = 0; j < DOUT; ++j) ols[j] = bs[DOUT + j] + d2 * acc[DOUT + j];
}

__global__ void k_scatterF(const int* __restrict__ src, const int* __restrict__ dst,
                           const float* __restrict__ dinv, const float* __restrict__ proj,
                           float* __restrict__ out, int e_cnt, int n) {
    long long gid = (long long)blockIdx.x * blockDim.x + threadIdx.x;
    int e = (int)(gid >> 5);
    int j = (int)(gid & 31);
    if (e >= e_cnt) return;
    int s = src[e], d = dst[e];
    float norm = dinv[s] * dinv[d];
    float v = norm * proj[(size_t)s * DC + j];
    float* o = (j < DOUT) ? (out + (size_t)d * DOUT + j)
                          : (out + (size_t)n * DOUT + (size_t)d * DOUT + (j - DOUT));
    unsafeAtomicAdd(o, v);
}

// ---------- launch ----------

extern "C" void kernel_launch(void* const* d_in, const int* in_sizes, int n_in,
                              void* d_out, int out_size, void* d_ws, size_t ws_size,
                              hipStream_t stream) {
    const float* x   = (const float*)d_in[0];
    const int*   ei  = (const int*)d_in[1];
    const float* Wmu = (const float*)d_in[2];
    const float* bmu = (const float*)d_in[3];
    const float* Wls = (const float*)d_in[4];
    const float* bls = (const float*)d_in[5];
    float* out = (float*)d_out;

    int n = in_sizes[0] / DIN;       // 100000
    int e_cnt = in_sizes[1] / 2;     // 1600000
    const int* src = ei;
    const int* dst = ei + e_cnt;

    int nb = (n + BNODES - 1) >> BSH;   // 782 buckets
    bool pack_ok = (n <= (1 << 17));

    size_t need = (size_t)NBP * 4               /* bfill    */
                + (size_t)n * 4                 /* dinv     */
                + (size_t)n * 4                 /* nodeinfo */
                + (size_t)nb * CAPB * 4         /* ebuf     */
                + (size_t)nb * CAPB * 4         /* esrc     */
                + (size_t)n * DC * 2;           /* projh    */

    int nblk = (n + 255) / 256;
    int eblk = (e_cnt + 255) / 256;

    if (nb <= NBP && pack_ok && ws_size >= need) {
        char* w = (char*)d_ws;
        int*    bfill = (int*)w;     w += NBP * 4;
        float*  dinv  = (float*)w;   w += (size_t)n * 4;
        uint*   ninfo = (uint*)w;    w += (size_t)n * 4;
        uint*   ebuf  = (uint*)w;    w += (size_t)nb * CAPB * 4;
        int*    esrc  = (int*)w;     w += (size_t)nb * CAPB * 4;
        ushort* projh = (ushort*)w;

        hipMemsetAsync(bfill, 0, NBP * sizeof(int), stream);
        int binblk = (e_cnt + EPB - 1) / EPB;
        k_bin2<<<binblk, TPB_BIN, 0, stream>>>(src, dst, bfill, ebuf, e_cnt, nb);
        k_sortproj<<<nb, 256, 0, stream>>>(ebuf, bfill, x, Wmu, Wls,
                                           ninfo, esrc, dinv, projh, n, nb);
        k_agg5<<<(n + 31) / 32, 256, 0, stream>>>(esrc, ninfo, dinv, projh,
                                                  bmu, bls, out, n);
    } else {
        float* deg  = (float*)d_ws;
        float* proj = deg + n;
        k_init_deg<<<nblk, 256, 0, stream>>>(deg, n);
        k_count<<<eblk, 256, 0, stream>>>(dst, deg, e_cnt);
        k_projF<<<nblk, 256, 0, stream>>>(x, Wmu, bmu, Wls, bls, deg, proj, out, n);
        long long tasks = (long long)e_cnt * DC;
        k_scatterF<<<(int)((tasks + 255) / 256), 256, 0, stream>>>(src, dst, deg, proj, out, e_cnt, n);
    }
}

// Round 14
// 71.770 us; speedup vs baseline: 1.0568x; 1.0568x over previous
//
#include <hip/hip_runtime.h>

#define DIN 48
#define DOUT 16
#define DC 32      // combined output dims: [mu(16) | logstd(16)]
#define BSH 7      // bucket shift: 128 nodes per bucket
#define BNODES 128
#define NBP 1024   // padded bucket count (power of 2, >= nb)
#define EPB 8192   // edges per binning block
#define TPB_BIN 1024
#define CAPB 4096  // fixed per-bucket region capacity (mean 2046, +45 sigma)
#define XS 49      // padded LDS stride for x tile (conflict-free)

typedef unsigned int uint;
typedef unsigned short ushort;
typedef ushort u16x8 __attribute__((ext_vector_type(8)));

__device__ __forceinline__ float b2f(ushort u) {
    union { uint i; float f; } v; v.i = ((uint)u) << 16; return v.f;
}
__device__ __forceinline__ ushort f2b(float f) {
    union { float f; uint i; } v; v.f = f;
    uint b = v.i;
    return (ushort)((b + 0x7FFFu + ((b >> 16) & 1u)) >> 16);  // round-to-nearest-even
}

// ---------- binning with atomic region reservation; edges cached in registers ----------

__global__ __launch_bounds__(TPB_BIN) void k_bin2(
        const int* __restrict__ src, const int* __restrict__ dst,
        int* __restrict__ bfill, uint* __restrict__ ebuf, int e_cnt, int nb) {
    __shared__ uint stageV[EPB];              // 32KB
    __shared__ ushort stageB[EPB];            // 16KB
    __shared__ int hist[NBP];                 // 4KB (reused as local fill)
    __shared__ int lofs[NBP];                 // 4KB
    __shared__ int gbase[NBP];                // 4KB
    __shared__ int wtot[16], woff[16];

    int t = threadIdx.x;
    int e0 = blockIdx.x * EPB;
    int ec = min(EPB, e_cnt - e0);

    hist[t] = 0;
    __syncthreads();

    // pass A: load edges ONCE into registers + local bucket histogram
    uint pv[8]; ushort pb[8];
#pragma unroll
    for (int it = 0; it < 8; ++it) {
        int k = t + TPB_BIN * it;
        if (k < ec) {
            int d = dst[e0 + k], s = src[e0 + k];
            int b = d >> BSH;
            pv[it] = ((uint)(d & (BNODES - 1)) << 17) | (uint)s;
            pb[it] = (ushort)b;
            atomicAdd(&hist[b], 1);
        }
    }
    __syncthreads();

    // wave-shuffle exclusive scan over 1024 bins (1 bin per thread, 16 waves)
    {
        int v = hist[t];
        int lane = t & 63, wid = t >> 6;
        int s_ = v;
#pragma unroll
        for (int off = 1; off < 64; off <<= 1) {
            int xv = __shfl_up(s_, off);
            if (lane >= off) s_ += xv;
        }
        if (lane == 63) wtot[wid] = s_;
        __syncthreads();
        if (t < 16) {
            int v2 = wtot[t];
            int w2 = v2;
#pragma unroll
            for (int off = 1; off < 16; off <<= 1) {
                int xv = __shfl_up(w2, off);
                if (t >= off) w2 += xv;
            }
            woff[t] = w2 - v2;
        }
        __syncthreads();
        lofs[t] = s_ - v + woff[wid];   // exclusive prefix for own bin
    }

    // reserve per-bucket region space: one atomic per nonempty bucket
    if (t < nb) {
        int h = hist[t];
        if (h > 0) gbase[t] = atomicAdd(&bfill[t], h);
    }
    __syncthreads();
    hist[t] = 0;  // becomes local fill counter
    __syncthreads();
    // pass B: stage packed edges (from registers) in bucket order
#pragma unroll
    for (int it = 0; it < 8; ++it) {
        int k = t + TPB_BIN * it;
        if (k < ec) {
            int b = pb[it];
            int p = atomicAdd(&hist[b], 1);
            int idx = lofs[b] + p;
            stageV[idx] = pv[it];
            stageB[idx] = pb[it];
        }
    }
    __syncthreads();
    // pass C: contiguous-run copy into the bucket's fixed region
    for (int i = t; i < ec; i += TPB_BIN) {
        int b = stageB[i];
        int off = gbase[b] + (i - lofs[b]);
        if (off < CAPB) ebuf[(size_t)b * CAPB + off] = stageV[i];
    }
}

// ---------- fused: per-bucket node sort -> CSR + dinv, then projection ----------

struct SortStage { uint in[CAPB]; int out[CAPB]; };   // 32KB
union SmemU { SortStage s; float xl[BNODES * XS]; };  // xl = 25088B, fits

__global__ __launch_bounds__(256) void k_sortproj(
        const uint* __restrict__ ebuf, const int* __restrict__ bfill,
        const float* __restrict__ x,
        const float* __restrict__ Wmu, const float* __restrict__ Wls,
        uint* __restrict__ nodeinfo, int* __restrict__ esrc,
        float* __restrict__ dinv, ushort* __restrict__ projh, int n, int nb) {
    __shared__ SmemU u;
    __shared__ float Wl[DIN * DC];            // 6144B
    __shared__ int cntl[BNODES], lofs[BNODES], fill[BNODES], sc[BNODES];
    __shared__ float dvl[BNODES];

    int b = blockIdx.x, t = threadIdx.x;
    int base = b << BSH;

    // ---- issue x-tile loads EARLY (async split: consume after sort) ----
    float4 xr[6];
#pragma unroll
    for (int it = 0; it < 6; ++it) {
        int f4 = t + 256 * it;
        int fb = f4 * 4;
        int node = fb / DIN, k2 = fb % DIN;
        int g = base + node;
        if (g < n) xr[it] = *reinterpret_cast<const float4*>(x + (size_t)g * DIN + k2);
    }

    // stage W (independent of sort phase)
    for (int idx = t; idx < DIN * DC; idx += 256) {
        int k = idx >> 5, j = idx & 31;
        Wl[idx] = (j < DOUT) ? Wmu[k * DOUT + j] : Wls[k * DOUT + (j - DOUT)];
    }

    int m = min(bfill[b], CAPB);

    if (t < BNODES) { cntl[t] = 0; fill[t] = 0; }
    __syncthreads();

    // load bucket segment + per-node histogram
    for (int i = t; i < m; i += 256) {
        uint pk = ebuf[(size_t)b * CAPB + i];
        u.s.in[i] = pk;
        atomicAdd(&cntl[pk >> 17], 1);
    }
    __syncthreads();

    // exclusive scan of 128 local counts
    if (t < BNODES) sc[t] = cntl[t];
    __syncthreads();
#pragma unroll
    for (int off = 1; off < BNODES; off <<= 1) {
        int v = (t < BNODES && t >= off) ? sc[t - off] : 0;
        __syncthreads();
        if (t < BNODES) sc[t] += v;
        __syncthreads();
    }
    if (t < BNODES) {
        int lo = sc[t] - cntl[t];
        lofs[t] = lo;
        int d = base + t;
        if (d < n) {
            nodeinfo[d] = (uint)lo | ((uint)cntl[t] << 13);
            float dv = rsqrtf(1.0f + (float)cntl[t]);
            dinv[d] = dv;
            dvl[t] = dv;
        }
    }
    __syncthreads();

    // placement: sorted by local node into stage_out
    for (int i = t; i < m; i += 256) {
        uint pk = u.s.in[i];
        int ln = (int)(pk >> 17);
        int s = (int)(pk & 0x1FFFFu);
        int r = atomicAdd(&fill[ln], 1);
        u.s.out[lofs[ln] + r] = s;
    }
    __syncthreads();

    // coalesced writeback into the bucket's esrc region
    for (int i = t; i < m; i += 256) esrc[(size_t)b * CAPB + i] = u.s.out[i];
    __syncthreads();

    // ---- projection phase: write prefetched x regs into (reused) LDS ----
#pragma unroll
    for (int it = 0; it < 6; ++it) {
        int f4 = t + 256 * it;
        int fb = f4 * 4;
        int node = fb / DIN, k2 = fb % DIN;
        int g = base + node;
        if (g < n) {
            float* p = &u.xl[node * XS + k2];
            p[0] = xr[it].x; p[1] = xr[it].y; p[2] = xr[it].z; p[3] = xr[it].w;
        }
    }
    __syncthreads();

    int nc = t & 7;        // col group: cols nc*4 .. nc*4+3
    int nr = t >> 3;       // node group: nodes nr*4 .. nr*4+3
    int c0 = nc * 4;

    float4 acc[4];
#pragma unroll
    for (int q = 0; q < 4; ++q) acc[q] = make_float4(0.f, 0.f, 0.f, 0.f);

#pragma unroll 4
    for (int k = 0; k < DIN; ++k) {
        float4 w = *reinterpret_cast<const float4*>(&Wl[k * DC + c0]);
#pragma unroll
        for (int q = 0; q < 4; ++q) {
            float xv = u.xl[(nr * 4 + q) * XS + k];
            acc[q].x += xv * w.x;
            acc[q].y += xv * w.y;
            acc[q].z += xv * w.z;
            acc[q].w += xv * w.w;
        }
    }

#pragma unroll
    for (int q = 0; q < 4; ++q) {
        int ln = nr * 4 + q;
        int d = base + ln;
        if (d >= n) continue;
        float dv = dvl[ln];
        ushort4 ph;
        ph.x = f2b(dv * acc[q].x); ph.y = f2b(dv * acc[q].y);
        ph.z = f2b(dv * acc[q].z); ph.w = f2b(dv * acc[q].w);
        *reinterpret_cast<ushort4*>(projh + ((size_t)d << 5) + c0) = ph;
    }
}

// ---------- gather aggregation: 4 lanes/node, ushort8 -> 128 lines in flight/wave ----------
// out[d][j] = bias[j] + dinv[d] * (projh[d][j] + sum_s projh[s][j])

__global__ __launch_bounds__(256) void k_agg6(
        const int* __restrict__ esrc, const uint* __restrict__ nodeinfo,
        const float* __restrict__ dinv, const ushort* __restrict__ projh,
        const float* __restrict__ bmu, const float* __restrict__ bls,
        float* __restrict__ out, int n) {
    int t = threadIdx.x;
    int l = t & 3;             // dim-octet lane: dims l*8 .. l*8+7
    int g = t >> 2;            // node slot within block (0..63)
    int d = blockIdx.x * 64 + g;
    if (d >= n) return;
    uint info = nodeinfo[d];
    int start = (d >> BSH) * CAPB + (int)(info & 0x1FFFu);
    int end = start + (int)(info >> 13);
    int c0 = l * 8;

    // self-loop term (pre-scaled by dinv[d])
    float acc[8];
    {
        u16x8 s8 = *reinterpret_cast<const u16x8*>(projh + ((size_t)d << 5) + c0);
#pragma unroll
        for (int q = 0; q < 8; ++q) acc[q] = b2f(s8[q]);
    }

    int k = start;
    int nxt[8];
    if (k + 8 <= end) {
#pragma unroll
        for (int u2 = 0; u2 < 8; ++u2) nxt[u2] = esrc[k + u2];
    }
    while (k + 8 <= end) {
        int cur[8];
#pragma unroll
        for (int u2 = 0; u2 < 8; ++u2) cur[u2] = nxt[u2];
        int k2 = k + 8;
        if (k2 + 8 <= end) {
#pragma unroll
            for (int u2 = 0; u2 < 8; ++u2) nxt[u2] = esrc[k2 + u2];
        }
        u16x8 p[8];
#pragma unroll
        for (int u2 = 0; u2 < 8; ++u2)
            p[u2] = *reinterpret_cast<const u16x8*>(projh + ((size_t)cur[u2] << 5) + c0);
#pragma unroll
        for (int u2 = 0; u2 < 8; ++u2) {
#pragma unroll
            for (int q = 0; q < 8; ++q) acc[q] += b2f(p[u2][q]);
        }
        k = k2;
    }
    for (; k < end; ++k) {
        int s = esrc[k];
        u16x8 pv = *reinterpret_cast<const u16x8*>(projh + ((size_t)s << 5) + c0);
#pragma unroll
        for (int q = 0; q < 8; ++q) acc[q] += b2f(pv[q]);
    }

    float dv = dinv[d];
    const float* bp = (l < 2) ? (bmu + c0) : (bls + (c0 - DOUT));
    float* o = (l < 2) ? (out + (size_t)d * DOUT + c0)
                       : (out + (size_t)n * DOUT + (size_t)d * DOUT + (c0 - DOUT));
    float4 o0, o1;
    o0.x = bp[0] + dv * acc[0]; o0.y = bp[1] + dv * acc[1];
    o0.z = bp[2] + dv * acc[2]; o0.w = bp[3] + dv * acc[3];
    o1.x = bp[4] + dv * acc[4]; o1.y = bp[5] + dv * acc[5];
    o1.z = bp[6] + dv * acc[6]; o1.w = bp[7] + dv * acc[7];
    *reinterpret_cast<float4*>(o) = o0;
    *reinterpret_cast<float4*>(o + 4) = o1;
}

// ---------- fallback (round-1 atomic) path ----------

__global__ void k_init_deg(float* __restrict__ deg, int n) {
    int i = blockIdx.x * blockDim.x + threadIdx.x;
    if (i < n) deg[i] = 1.0f;
}

__global__ void k_count(const int* __restrict__ dst, float* __restrict__ deg, int e_cnt) {
    int e = blockIdx.x * blockDim.x + threadIdx.x;
    if (e < e_cnt) unsafeAtomicAdd(&deg[dst[e]], 1.0f);
}

__global__ void k_projF(const float* __restrict__ x,
                        const float* __restrict__ Wmu, const float* __restrict__ bmu,
                        const float* __restrict__ Wls, const float* __restrict__ bls,
                        float* __restrict__ deg_dinv, float* __restrict__ proj,
                        float* __restrict__ out, int n) {
    __shared__ float Ws[DIN * DC];
    __shared__ float bs[DC];
    int t = threadIdx.x;
    for (int idx = t; idx < DIN * DC; idx += blockDim.x) {
        int k = idx >> 5, j = idx & 31;
        Ws[idx] = (j < DOUT) ? Wmu[k * DOUT + j] : Wls[k * DOUT + (j - DOUT)];
    }
    if (t < DC) bs[t] = (t < DOUT) ? bmu[t] : bls[t - DOUT];
    __syncthreads();
    int i = blockIdx.x * blockDim.x + t;
    if (i >= n) return;
    float xr[DIN];
    const float4* xp = reinterpret_cast<const float4*>(x + (size_t)i * DIN);
#pragma unroll
    for (int q = 0; q < DIN / 4; ++q) {
        float4 v = xp[q];
        xr[4 * q + 0] = v.x; xr[4 * q + 1] = v.y;
        xr[4 * q + 2] = v.z; xr[4 * q + 3] = v.w;
    }
    float acc[DC];
#pragma unroll
    for (int j = 0; j < DC; ++j) acc[j] = 0.0f;
#pragma unroll 4
    for (int k = 0; k < DIN; ++k) {
        float xv = xr[k];
#pragma unroll
        for (int j = 0; j < DC; ++j) acc[j] += xv * Ws[k * DC + j];
    }
    float dv = rsqrtf(deg_dinv[i]);
    deg_dinv[i] = dv;
    float d2 = dv * dv;
    float4* pp = reinterpret_cast<float4*>(proj + (size_t)i * DC);
#pragma unroll
    for (int q = 0; q < DC / 4; ++q) {
        float4 v;
        v.x = acc[4 * q + 0]; v.y = acc[4 * q + 1];
        v.z = acc[4 * q + 2]; v.w = acc[4 * q + 3];
        pp[q] = v;
    }
    float* omu = out + (size_t)i * DOUT;
    float* ols = out + (size_t)n * DOUT + (size_t)i * DOUT;
#pragma unroll
    for (int j = 0; j < DOUT; ++j) omu[j] = bs[j] + d2 * acc[j];
#pragma unroll
    for (int j = 0; j < DOUT; ++j) ols[j] = bs[DOUT + j] + d2 * acc[DOUT + j];
}

__global__ void k_scatterF(const int* __restrict__ src, const int* __restrict__ dst,
                           const float* __restrict__ dinv, const float* __restrict__ proj,
                           float* __restrict__ out, int e_cnt, int n) {
    long long gid = (long long)blockIdx.x * blockDim.x + threadIdx.x;
    int e = (int)(gid >> 5);
    int j = (int)(gid & 31);
    if (e >= e_cnt) return;
    int s = src[e], d = dst[e];
    float norm = dinv[s] * dinv[d];
    float v = norm * proj[(size_t)s * DC + j];
    float* o = (j < DOUT) ? (out + (size_t)d * DOUT + j)
                          : (out + (size_t)n * DOUT + (size_t)d * DOUT + (j - DOUT));
    unsafeAtomicAdd(o, v);
}

// ---------- launch ----------

extern "C" void kernel_launch(void* const* d_in, const int* in_sizes, int n_in,
                              void* d_out, int out_size, void* d_ws, size_t ws_size,
                              hipStream_t stream) {
    const float* x   = (const float*)d_in[0];
    const int*   ei  = (const int*)d_in[1];
    const float* Wmu = (const float*)d_in[2];
    const float* bmu = (const float*)d_in[3];
    const float* Wls = (const float*)d_in[4];
    const float* bls = (const float*)d_in[5];
    float* out = (float*)d_out;

    int n = in_sizes[0] / DIN;       // 100000
    int e_cnt = in_sizes[1] / 2;     // 1600000
    const int* src = ei;
    const int* dst = ei + e_cnt;

    int nb = (n + BNODES - 1) >> BSH;   // 782 buckets
    bool pack_ok = (n <= (1 << 17));

    size_t need = (size_t)NBP * 4               /* bfill    */
                + (size_t)n * 4                 /* dinv     */
                + (size_t)n * 4                 /* nodeinfo */
                + (size_t)nb * CAPB * 4         /* ebuf     */
                + (size_t)nb * CAPB * 4         /* esrc     */
                + (size_t)n * DC * 2;           /* projh    */

    int nblk = (n + 255) / 256;
    int eblk = (e_cnt + 255) / 256;

    if (nb <= NBP && pack_ok && ws_size >= need) {
        char* w = (char*)d_ws;
        int*    bfill = (int*)w;     w += NBP * 4;
        float*  dinv  = (float*)w;   w += (size_t)n * 4;
        uint*   ninfo = (uint*)w;    w += (size_t)n * 4;
        uint*   ebuf  = (uint*)w;    w += (size_t)nb * CAPB * 4;
        int*    esrc  = (int*)w;     w += (size_t)nb * CAPB * 4;
        ushort* projh = (ushort*)w;

        hipMemsetAsync(bfill, 0, NBP * sizeof(int), stream);
        int binblk = (e_cnt + EPB - 1) / EPB;
        k_bin2<<<binblk, TPB_BIN, 0, stream>>>(src, dst, bfill, ebuf, e_cnt, nb);
        k_sortproj<<<nb, 256, 0, stream>>>(ebuf, bfill, x, Wmu, Wls,
                                           ninfo, esrc, dinv, projh, n, nb);
        k_agg6<<<(n + 63) / 64, 256, 0, stream>>>(esrc, ninfo, dinv, projh,
                                                  bmu, bls, out, n);
    } else {
        float* deg  = (float*)d_ws;
        float* proj = deg + n;
        k_init_deg<<<nblk, 256, 0, stream>>>(deg, n);
        k_count<<<eblk, 256, 0, stream>>>(dst, deg, e_cnt);
        k_projF<<<nblk, 256, 0, stream>>>(x, Wmu, bmu, Wls, bls, deg, proj, out, n);
        long long tasks = (long long)e_cnt * DC;
        k_scatterF<<<(int)((tasks + 255) / 256), 256, 0, stream>>>(src, dst, deg, proj, out, e_cnt, n);
    }
}

// Round 15
// 69.804 us; speedup vs baseline: 1.0866x; 1.0282x over previous
//
#include <hip/hip_runtime.h>

#define DIN 48
#define DOUT 16
#define DC 32      // combined output dims: [mu(16) | logstd(16)]
#define BSH 7      // bucket shift: 128 nodes per bucket
#define BNODES 128
#define NBP 1024   // padded bucket count (power of 2, >= nb)
#define EPB 8192   // edges per binning block
#define TPB_BIN 1024
#define CAPB 4096  // fixed per-bucket region capacity (mean 2046, +45 sigma)
#define XS 49      // padded LDS stride for x tile (conflict-free)

typedef unsigned int uint;
typedef unsigned short ushort;

__device__ __forceinline__ float b2f(ushort u) {
    union { uint i; float f; } v; v.i = ((uint)u) << 16; return v.f;
}
__device__ __forceinline__ ushort f2b(float f) {
    union { float f; uint i; } v; v.f = f;
    uint b = v.i;
    return (ushort)((b + 0x7FFFu + ((b >> 16) & 1u)) >> 16);  // round-to-nearest-even
}

// ---------- binning: rank captured from pass-A atomicAdd (single LDS-atomic pass) ----------

__global__ __launch_bounds__(TPB_BIN) void k_bin2(
        const int* __restrict__ src, const int* __restrict__ dst,
        int* __restrict__ bfill, uint* __restrict__ ebuf, int e_cnt, int nb) {
    __shared__ uint stageV[EPB];              // 32KB
    __shared__ ushort stageB[EPB];            // 16KB
    __shared__ int hist[NBP];                 // 4KB
    __shared__ int lofs[NBP];                 // 4KB
    __shared__ int gbase[NBP];                // 4KB
    __shared__ int wtot[16], woff[16];

    int t = threadIdx.x;
    int e0 = blockIdx.x * EPB;
    int ec = min(EPB, e_cnt - e0);

    hist[t] = 0;
    __syncthreads();

    // pass A: load edges ONCE into registers + histogram; atomicAdd return = in-bucket rank
    uint pv[8]; ushort pb[8]; ushort prank[8];
#pragma unroll
    for (int it = 0; it < 8; ++it) {
        int k = t + TPB_BIN * it;
        if (k < ec) {
            int d = dst[e0 + k], s = src[e0 + k];
            int b = d >> BSH;
            pv[it] = ((uint)(d & (BNODES - 1)) << 17) | (uint)s;
            pb[it] = (ushort)b;
            prank[it] = (ushort)atomicAdd(&hist[b], 1);
        }
    }
    __syncthreads();

    // wave-shuffle exclusive scan over 1024 bins (1 bin per thread, 16 waves)
    {
        int v = hist[t];
        int lane = t & 63, wid = t >> 6;
        int s_ = v;
#pragma unroll
        for (int off = 1; off < 64; off <<= 1) {
            int xv = __shfl_up(s_, off);
            if (lane >= off) s_ += xv;
        }
        if (lane == 63) wtot[wid] = s_;
        __syncthreads();
        if (t < 16) {
            int v2 = wtot[t];
            int w2 = v2;
#pragma unroll
            for (int off = 1; off < 16; off <<= 1) {
                int xv = __shfl_up(w2, off);
                if (t >= off) w2 += xv;
            }
            woff[t] = w2 - v2;
        }
        __syncthreads();
        lofs[t] = s_ - v + woff[wid];   // exclusive prefix for own bin
    }

    // reserve per-bucket region space: one atomic per nonempty bucket
    if (t < nb) {
        int h = hist[t];
        if (h > 0) gbase[t] = atomicAdd(&bfill[t], h);
    }
    __syncthreads();

    // pass B: pure computed writes (no second atomic pass)
#pragma unroll
    for (int it = 0; it < 8; ++it) {
        int k = t + TPB_BIN * it;
        if (k < ec) {
            int idx = lofs[pb[it]] + (int)prank[it];
            stageV[idx] = pv[it];
            stageB[idx] = pb[it];
        }
    }
    __syncthreads();
    // pass C: contiguous-run copy into the bucket's fixed region
    for (int i = t; i < ec; i += TPB_BIN) {
        int b = stageB[i];
        int off = gbase[b] + (i - lofs[b]);
        if (off < CAPB) ebuf[(size_t)b * CAPB + off] = stageV[i];
    }
}

// ---------- fused: per-bucket node sort -> CSR + dinv, then projection ----------

struct SortStage { uint in[CAPB]; int out[CAPB]; };   // 32KB
union SmemU { SortStage s; float xl[BNODES * XS]; };  // xl = 25088B, fits

__global__ __launch_bounds__(256) void k_sortproj(
        const uint* __restrict__ ebuf, const int* __restrict__ bfill,
        const float* __restrict__ x,
        const float* __restrict__ Wmu, const float* __restrict__ Wls,
        uint* __restrict__ nodeinfo, int* __restrict__ esrc,
        float* __restrict__ dinv, ushort* __restrict__ projh, int n, int nb) {
    __shared__ SmemU u;
    __shared__ float Wl[DIN * DC];            // 6144B
    __shared__ int cntl[BNODES], lofs[BNODES], fill[BNODES], sc[BNODES];
    __shared__ float dvl[BNODES];

    int b = blockIdx.x, t = threadIdx.x;
    int base = b << BSH;

    // ---- issue x-tile loads EARLY (async split: consume after sort) ----
    float4 xr[6];
#pragma unroll
    for (int it = 0; it < 6; ++it) {
        int f4 = t + 256 * it;
        int fb = f4 * 4;
        int node = fb / DIN, k2 = fb % DIN;
        int g = base + node;
        if (g < n) xr[it] = *reinterpret_cast<const float4*>(x + (size_t)g * DIN + k2);
    }

    // stage W (independent of sort phase)
    for (int idx = t; idx < DIN * DC; idx += 256) {
        int k = idx >> 5, j = idx & 31;
        Wl[idx] = (j < DOUT) ? Wmu[k * DOUT + j] : Wls[k * DOUT + (j - DOUT)];
    }

    int m = min(bfill[b], CAPB);

    if (t < BNODES) { cntl[t] = 0; fill[t] = 0; }
    __syncthreads();

    // load bucket segment + per-node histogram
    for (int i = t; i < m; i += 256) {
        uint pk = ebuf[(size_t)b * CAPB + i];
        u.s.in[i] = pk;
        atomicAdd(&cntl[pk >> 17], 1);
    }
    __syncthreads();

    // exclusive scan of 128 local counts
    if (t < BNODES) sc[t] = cntl[t];
    __syncthreads();
#pragma unroll
    for (int off = 1; off < BNODES; off <<= 1) {
        int v = (t < BNODES && t >= off) ? sc[t - off] : 0;
        __syncthreads();
        if (t < BNODES) sc[t] += v;
        __syncthreads();
    }
    if (t < BNODES) {
        int lo = sc[t] - cntl[t];
        lofs[t] = lo;
        int d = base + t;
        if (d < n) {
            nodeinfo[d] = (uint)lo | ((uint)cntl[t] << 13);
            float dv = rsqrtf(1.0f + (float)cntl[t]);
            dinv[d] = dv;
            dvl[t] = dv;
        }
    }
    __syncthreads();

    // placement: sorted by local node into stage_out
    for (int i = t; i < m; i += 256) {
        uint pk = u.s.in[i];
        int ln = (int)(pk >> 17);
        int s = (int)(pk & 0x1FFFFu);
        int r = atomicAdd(&fill[ln], 1);
        u.s.out[lofs[ln] + r] = s;
    }
    __syncthreads();

    // coalesced writeback into the bucket's esrc region
    for (int i = t; i < m; i += 256) esrc[(size_t)b * CAPB + i] = u.s.out[i];
    __syncthreads();

    // ---- projection phase: write prefetched x regs into (reused) LDS ----
#pragma unroll
    for (int it = 0; it < 6; ++it) {
        int f4 = t + 256 * it;
        int fb = f4 * 4;
        int node = fb / DIN, k2 = fb % DIN;
        int g = base + node;
        if (g < n) {
            float* p = &u.xl[node * XS + k2];
            p[0] = xr[it].x; p[1] = xr[it].y; p[2] = xr[it].z; p[3] = xr[it].w;
        }
    }
    __syncthreads();

    int nc = t & 7;        // col group: cols nc*4 .. nc*4+3
    int nr = t >> 3;       // node group: nodes nr*4 .. nr*4+3
    int c0 = nc * 4;

    float4 acc[4];
#pragma unroll
    for (int q = 0; q < 4; ++q) acc[q] = make_float4(0.f, 0.f, 0.f, 0.f);

#pragma unroll 4
    for (int k = 0; k < DIN; ++k) {
        float4 w = *reinterpret_cast<const float4*>(&Wl[k * DC + c0]);
#pragma unroll
        for (int q = 0; q < 4; ++q) {
            float xv = u.xl[(nr * 4 + q) * XS + k];
            acc[q].x += xv * w.x;
            acc[q].y += xv * w.y;
            acc[q].z += xv * w.z;
            acc[q].w += xv * w.w;
        }
    }

#pragma unroll
    for (int q = 0; q < 4; ++q) {
        int ln = nr * 4 + q;
        int d = base + ln;
        if (d >= n) continue;
        float dv = dvl[ln];
        ushort4 ph;
        ph.x = f2b(dv * acc[q].x); ph.y = f2b(dv * acc[q].y);
        ph.z = f2b(dv * acc[q].z); ph.w = f2b(dv * acc[q].w);
        *reinterpret_cast<ushort4*>(projh + ((size_t)d << 5) + c0) = ph;
    }
}

// ---------- gather aggregation: 8 lanes/node, esrc double-buffered pipeline ----------
// out[d][j] = bias[j] + dinv[d] * (projh[d][j] + sum_s projh[s][j])

__global__ __launch_bounds__(256) void k_agg5(
        const int* __restrict__ esrc, const uint* __restrict__ nodeinfo,
        const float* __restrict__ dinv, const ushort* __restrict__ projh,
        const float* __restrict__ bmu, const float* __restrict__ bls,
        float* __restrict__ out, int n) {
    int t = threadIdx.x;
    int l = t & 7;             // dim-quad lane: dims l*4 .. l*4+3
    int g = t >> 3;            // node slot within block (0..31)
    int d = blockIdx.x * 32 + g;
    if (d >= n) return;
    uint info = nodeinfo[d];
    int start = (d >> BSH) * CAPB + (int)(info & 0x1FFFu);
    int end = start + (int)(info >> 13);
    int c0 = l * 4;

    // self-loop term (pre-scaled by dinv[d])
    float4 acc;
    {
        ushort4 s4 = *reinterpret_cast<const ushort4*>(projh + ((size_t)d << 5) + c0);
        acc.x = b2f(s4.x); acc.y = b2f(s4.y); acc.z = b2f(s4.z); acc.w = b2f(s4.w);
    }

    int k = start;
    int nxt[8];
    if (k + 8 <= end) {
#pragma unroll
        for (int u2 = 0; u2 < 8; ++u2) nxt[u2] = esrc[k + u2];
    }
    while (k + 8 <= end) {
        int cur[8];
#pragma unroll
        for (int u2 = 0; u2 < 8; ++u2) cur[u2] = nxt[u2];
        int k2 = k + 8;
        if (k2 + 8 <= end) {
#pragma unroll
            for (int u2 = 0; u2 < 8; ++u2) nxt[u2] = esrc[k2 + u2];
        }
        ushort4 p[8];
#pragma unroll
        for (int u2 = 0; u2 < 8; ++u2)
            p[u2] = *reinterpret_cast<const ushort4*>(projh + ((size_t)cur[u2] << 5) + c0);
#pragma unroll
        for (int u2 = 0; u2 < 8; ++u2) {
            acc.x += b2f(p[u2].x); acc.y += b2f(p[u2].y);
            acc.z += b2f(p[u2].z); acc.w += b2f(p[u2].w);
        }
        k = k2;
    }
    for (; k < end; ++k) {
        int s = esrc[k];
        ushort4 pv = *reinterpret_cast<const ushort4*>(projh + ((size_t)s << 5) + c0);
        acc.x += b2f(pv.x); acc.y += b2f(pv.y); acc.z += b2f(pv.z); acc.w += b2f(pv.w);
    }

    float dv = dinv[d];
    float4 bias = (l < 4) ? *reinterpret_cast<const float4*>(bmu + c0)
                          : *reinterpret_cast<const float4*>(bls + (c0 - DOUT));
    float4 ov;
    ov.x = bias.x + dv * acc.x; ov.y = bias.y + dv * acc.y;
    ov.z = bias.z + dv * acc.z; ov.w = bias.w + dv * acc.w;
    float* o = (l < 4) ? (out + (size_t)d * DOUT + c0)
                       : (out + (size_t)n * DOUT + (size_t)d * DOUT + (c0 - DOUT));
    *reinterpret_cast<float4*>(o) = ov;
}

// ---------- fallback (round-1 atomic) path ----------

__global__ void k_init_deg(float* __restrict__ deg, int n) {
    int i = blockIdx.x * blockDim.x + threadIdx.x;
    if (i < n) deg[i] = 1.0f;
}

__global__ void k_count(const int* __restrict__ dst, float* __restrict__ deg, int e_cnt) {
    int e = blockIdx.x * blockDim.x + threadIdx.x;
    if (e < e_cnt) unsafeAtomicAdd(&deg[dst[e]], 1.0f);
}

__global__ void k_projF(const float* __restrict__ x,
                        const float* __restrict__ Wmu, const float* __restrict__ bmu,
                        const float* __restrict__ Wls, const float* __restrict__ bls,
                        float* __restrict__ deg_dinv, float* __restrict__ proj,
                        float* __restrict__ out, int n) {
    __shared__ float Ws[DIN * DC];
    __shared__ float bs[DC];
    int t = threadIdx.x;
    for (int idx = t; idx < DIN * DC; idx += blockDim.x) {
        int k = idx >> 5, j = idx & 31;
        Ws[idx] = (j < DOUT) ? Wmu[k * DOUT + j] : Wls[k * DOUT + (j - DOUT)];
    }
    if (t < DC) bs[t] = (t < DOUT) ? bmu[t] : bls[t - DOUT];
    __syncthreads();
    int i = blockIdx.x * blockDim.x + t;
    if (i >= n) return;
    float xr[DIN];
    const float4* xp = reinterpret_cast<const float4*>(x + (size_t)i * DIN);
#pragma unroll
    for (int q = 0; q < DIN / 4; ++q) {
        float4 v = xp[q];
        xr[4 * q + 0] = v.x; xr[4 * q + 1] = v.y;
        xr[4 * q + 2] = v.z; xr[4 * q + 3] = v.w;
    }
    float acc[DC];
#pragma unroll
    for (int j = 0; j < DC; ++j) acc[j] = 0.0f;
#pragma unroll 4
    for (int k = 0; k < DIN; ++k) {
        float xv = xr[k];
#pragma unroll
        for (int j = 0; j < DC; ++j) acc[j] += xv * Ws[k * DC + j];
    }
    float dv = rsqrtf(deg_dinv[i]);
    deg_dinv[i] = dv;
    float d2 = dv * dv;
    float4* pp = reinterpret_cast<float4*>(proj + (size_t)i * DC);
#pragma unroll
    for (int q = 0; q < DC / 4; ++q) {
        float4 v;
        v.x = acc[4 * q + 0]; v.y = acc[4 * q + 1];
        v.z = acc[4 * q + 2]; v.w = acc[4 * q + 3];
        pp[q] = v;
    }
    float* omu = out + (size_t)i * DOUT;
    float* ols = out + (size_t)n * DOUT + (size_t)i * DOUT;
#pragma unroll
    for (int j = 0; j < DOUT; ++j) omu[j] = bs[j] + d2 * acc[j];
#pragma unroll
    for (int j = 0; j < DOUT; ++j) ols[j] = bs[DOUT + j] + d2 * acc[DOUT + j];
}

__global__ void k_scatterF(const int* __restrict__ src, const int* __restrict__ dst,
                           const float* __restrict__ dinv, const float* __restrict__ proj,
                           float* __restrict__ out, int e_cnt, int n) {
    long long gid = (long long)blockIdx.x * blockDim.x + threadIdx.x;
    int e = (int)(gid >> 5);
    int j = (int)(gid & 31);
    if (e >= e_cnt) return;
    int s = src[e], d = dst[e];
    float norm = dinv[s] * dinv[d];
    float v = norm * proj[(size_t)s * DC + j];
    float* o = (j < DOUT) ? (out + (size_t)d * DOUT + j)
                          : (out + (size_t)n * DOUT + (size_t)d * DOUT + (j - DOUT));
    unsafeAtomicAdd(o, v);
}

// ---------- launch ----------

extern "C" void kernel_launch(void* const* d_in, const int* in_sizes, int n_in,
                              void* d_out, int out_size, void* d_ws, size_t ws_size,
                              hipStream_t stream) {
    const float* x   = (const float*)d_in[0];
    const int*   ei  = (const int*)d_in[1];
    const float* Wmu = (const float*)d_in[2];
    const float* bmu = (const float*)d_in[3];
    const float* Wls = (const float*)d_in[4];
    const float* bls = (const float*)d_in[5];
    float* out = (float*)d_out;

    int n = in_sizes[0] / DIN;       // 100000
    int e_cnt = in_sizes[1] / 2;     // 1600000
    const int* src = ei;
    const int* dst = ei + e_cnt;

    int nb = (n + BNODES - 1) >> BSH;   // 782 buckets
    bool pack_ok = (n <= (1 << 17));

    size_t need = (size_t)NBP * 4               /* bfill    */
                + (size_t)n * 4                 /* dinv     */
                + (size_t)n * 4                 /* nodeinfo */
                + (size_t)nb * CAPB * 4         /* ebuf     */
                + (size_t)nb * CAPB * 4         /* esrc     */
                + (size_t)n * DC * 2;           /* projh    */

    int nblk = (n + 255) / 256;
    int eblk = (e_cnt + 255) / 256;

    if (nb <= NBP && pack_ok && ws_size >= need) {
        char* w = (char*)d_ws;
        int*    bfill = (int*)w;     w += NBP * 4;
        float*  dinv  = (float*)w;   w += (size_t)n * 4;
        uint*   ninfo = (uint*)w;    w += (size_t)n * 4;
        uint*   ebuf  = (uint*)w;    w += (size_t)nb * CAPB * 4;
        int*    esrc  = (int*)w;     w += (size_t)nb * CAPB * 4;
        ushort* projh = (ushort*)w;

        hipMemsetAsync(bfill, 0, NBP * sizeof(int), stream);
        int binblk = (e_cnt + EPB - 1) / EPB;
        k_bin2<<<binblk, TPB_BIN, 0, stream>>>(src, dst, bfill, ebuf, e_cnt, nb);
        k_sortproj<<<nb, 256, 0, stream>>>(ebuf, bfill, x, Wmu, Wls,
                                           ninfo, esrc, dinv, projh, n, nb);
        k_agg5<<<(n + 31) / 32, 256, 0, stream>>>(esrc, ninfo, dinv, projh,
                                                  bmu, bls, out, n);
    } else {
        float* deg  = (float*)d_ws;
        float* proj = deg + n;
        k_init_deg<<<nblk, 256, 0, stream>>>(deg, n);
        k_count<<<eblk, 256, 0, stream>>>(dst, deg, e_cnt);
        k_projF<<<nblk, 256, 0, stream>>>(x, Wmu, bmu, Wls, bls, deg, proj, out, n);
        long long tasks = (long long)e_cnt * DC;
        k_scatterF<<<(int)((tasks + 255) / 256), 256, 0, stream>>>(src, dst, deg, proj, out, e_cnt, n);
    }
}